// Round 14
// baseline (1697.042 us; speedup 1.0000x reference)
//
#include <hip/hip_runtime.h>

#define DT_C 0.1f
#define LOG2E 1.4426950408889634f
#define S_ACC 1920   // drop acc for t<1920: |err| <= 0.9^128 ~ 1.4e-6 << 1.8e-2 threshold

typedef _Float16 h2 __attribute__((ext_vector_type(2)));

__device__ __forceinline__ float sigx(float z) {
    return __builtin_amdgcn_rcpf(1.0f + __builtin_amdgcn_exp2f(-LOG2E * z));
}
__device__ __forceinline__ float tanhx(float z) {
    return fmaf(2.0f, __builtin_amdgcn_rcpf(1.0f + __builtin_amdgcn_exp2f(-2.0f * LOG2E * z)), -1.0f);
}

template <int CTRL>
__device__ __forceinline__ float dpp_add(float v) {
    return v + __int_as_float(__builtin_amdgcn_update_dpp(0, __float_as_int(v), CTRL, 0xF, 0xF, true));
}
// 4-lane butterfly sum (aligned quads): xor1 (0xB1) + xor2 (0x4E).
__device__ __forceinline__ float red4(float v) {
    v = dpp_add<0xB1>(v);
    v = dpp_add<0x4E>(v);
    return v;
}
__device__ __forceinline__ float fdot2(h2 a, h2 b, float c) {
    return __builtin_amdgcn_fdot2(a, b, c, false);
}

// B=256, S=2048, I=1, H=128, O=1.
// R14: ROW-PAIRING. Grid 128 blocks x 256 threads; each block runs TWO batch
// rows (2r, 2r+1) interleaved in the same threads. Weights shared; h/acc
// states + LDS exchange buffers duplicated. Row B's independent dots/nonlins
// fill row A's stall windows (post-barrier ds latency, exp2/rcp latency) and
// vice versa — converts the structural ~350cyc/step stall (R11-R13: immune to
// issue reduction) into useful work. Half the CUs idle, but wall = 2 rows per
// block at ~chain-rate instead of 1.
// Per-row structure = R13 (verified): 2 exchanges/step, t=jg*4+ks quad roles,
// rows j0=jg/j1=jg+64, packed f16 k-pairs {m,m+64}, dual b16 publishes,
// folded exp2 args, off-chain h-precompute, dot2 matvecs, fp32 state.
__global__ __attribute__((amdgpu_waves_per_eu(1, 1))) __launch_bounds__(256)
void clnm_kernel(const float* __restrict__ x,      // [256,2048]
                 const float* __restrict__ W_in,   // [128,1]
                 const float* __restrict__ b_in,   // [128]
                 const float* __restrict__ W_rec,  // [128,128]
                 const float* __restrict__ b_rec,  // [128]
                 const float* __restrict__ tau,    // [128]
                 const float* __restrict__ W_att,  // [128,128]
                 const float* __restrict__ b_att,  // [128]
                 const float* __restrict__ W_ev,   // [1,2]
                 const float* __restrict__ b_ev,   // [1]
                 const float* __restrict__ W_acc,  // [128,128]
                 const float* __restrict__ b_acc,  // [128]
                 const float* __restrict__ W_out,  // [1,128]
                 const float* __restrict__ b_out,  // [1]
                 float* __restrict__ out,          // [256]
                 float* __restrict__ out_ew)       // [256,2048]
{
    const int t  = threadIdx.x;
    const int jg = t >> 2;        // 0..63
    const int ks = t & 3;         // 0..3 == role
    const int j0 = jg;
    const int j1 = jg + 64;
    const int rA = 2 * blockIdx.x;
    const int rB = rA + 1;

    __shared__ __align__(16) float    x_stage[2][2048];
    __shared__ __align__(16) float4   xe_lds[2][2048]; // {x_{s+1}, DT(1+ew), 0.1ew, ew}
    __shared__ __align__(16) unsigned h16A[64], ha16A[64];  // packed {v[m], v[m+64]} f16
    __shared__ __align__(16) unsigned h16B[64], ha16B[64];
    __shared__ float red_s[8];

    const float wev0 = W_ev[0], wev1 = W_ev[1], bev = b_ev[0], bout = b_out[0];

    ((float4*)&x_stage[0][0])[t]       = ((const float4*)(x + (size_t)rA * 2048))[t];
    ((float4*)&x_stage[0][0])[t + 256] = ((const float4*)(x + (size_t)rA * 2048))[t + 256];
    ((float4*)&x_stage[1][0])[t]       = ((const float4*)(x + (size_t)rB * 2048))[t];
    ((float4*)&x_stage[1][0])[t + 256] = ((const float4*)(x + (size_t)rB * 2048))[t + 256];
    if (t < 64) { h16A[t] = 0u; ha16A[t] = 0u; h16B[t] = 0u; ha16B[t] = 0u; }
    __syncthreads();

    // Per-step scalars for both rows, 8 steps/thread/row; out_ew coalesced.
#pragma unroll
    for (int rr = 0; rr < 2; ++rr) {
        const int s0 = t * 8;
        float xv[9];
#pragma unroll
        for (int i = 0; i < 8; ++i) xv[i] = x_stage[rr][s0 + i];
        xv[8] = (s0 + 8 < 2048) ? x_stage[rr][s0 + 8] : 0.0f;
        const float xm1 = (t == 0) ? 0.0f : x_stage[rr][s0 - 1];
        float e[8];
        e[0] = (s0 == 0) ? 0.0f : sigx(fmaf(wev0, xv[0], fmaf(wev1, xm1, bev)));
#pragma unroll
        for (int i = 1; i < 8; ++i)
            e[i] = sigx(fmaf(wev0, xv[i], fmaf(wev1, xv[i - 1], bev)));
#pragma unroll
        for (int i = 0; i < 8; ++i)
            xe_lds[rr][s0 + i] = make_float4(xv[i + 1], DT_C * (1.0f + e[i]), 0.1f * e[i], e[i]);
        float* ewp = out_ew + (size_t)(rA + rr) * 2048;
        ((float4*)ewp)[2 * t]     = make_float4(e[0], e[1], e[2], e[3]);
        ((float4*)ewp)[2 * t + 1] = make_float4(e[4], e[5], e[6], e[7]);
    }

    // Weights as half2 pairs {W[row][m], W[row][m+64]}, m = 16ks+i, i<16.
    h2 wA[2][16], wR[2][16], wC[2][16];
#pragma unroll
    for (int g = 0; g < 2; ++g) {
        const int base = (g ? j1 : j0) * 128 + 16 * ks;
#pragma unroll
        for (int i = 0; i < 16; ++i) {
            wA[g][i] = h2{(_Float16)W_att[base + i], (_Float16)W_att[base + 64 + i]};
            wR[g][i] = h2{(_Float16)W_rec[base + i], (_Float16)W_rec[base + 64 + i]};
            wC[g][i] = h2{(_Float16)W_acc[base + i], (_Float16)W_acc[base + 64 + i]};
        }
    }

    // Lane roles: 0: rec/att j0, 1: rec/att j1, 2: acc j0, 3: acc j1.
    const bool odd = (ks & 1) != 0;
    const bool low = (ks & 2) == 0;
    const float m2 = -2.0f * LOG2E;
    const float bRsel  = odd ? b_rec[j1] : b_rec[j0];
    const float winsel = odd ? W_in[j1]  : W_in[j0];
    const float binsel = odd ? b_in[j1]  : b_in[j0];
    const float bR2m   = m2 * bRsel;
    const float m2win  = m2 * winsel, m2bin = m2 * binsel;
    const float bAsel  = odd ? b_att[j1] : b_att[j0];
    const float bA1m   = -LOG2E * bAsel;
    const float bFsel  = low ? bAsel : (odd ? b_acc[j1] : b_acc[j0]);
    const float preF   = low ? -LOG2E : m2;
    const float preFb  = preF * bFsel;
    const float postm  = low ? 1.0f : 2.0f;
    const float posta  = low ? 0.0f : -1.0f;
    const float tisel  = 1.0f / fminf(fmaxf(odd ? tau[j1] : tau[j0], 0.1f), 10.0f);
    const float wosel  = odd ? W_out[j1] : W_out[j0];

    __syncthreads();   // zeros + xe_lds visible

    float hjsA = 0.0f, acsA = 0.0f, hjsB = 0.0f, acsB = 0.0f;
    float iccurA = tanhx(fmaf(x_stage[0][0], winsel, binsel));
    float iccurB = tanhx(fmaf(x_stage[1][0], winsel, binsel));

    const uint4* h4pA  = (const uint4*)h16A;
    const uint4* ha4pA = (const uint4*)ha16A;
    const uint4* h4pB  = (const uint4*)h16B;
    const uint4* ha4pB = (const uint4*)ha16B;
    _Float16* h16hA  = (_Float16*)h16A;
    _Float16* ha16hA = (_Float16*)ha16A;
    _Float16* h16hB  = (_Float16*)h16B;
    _Float16* ha16hB = (_Float16*)ha16B;

    for (int s = 0; s < 2048; ++s) {
        __syncthreads();   // A: hatt(h_s) visible for both rows (s=0: zeros)

        const uint4 aA0 = ha4pA[4 * ks + 0], aA1 = ha4pA[4 * ks + 1];
        const uint4 aA2 = ha4pA[4 * ks + 2], aA3 = ha4pA[4 * ks + 3];
        const uint4 aB0 = ha4pB[4 * ks + 0], aB1 = ha4pB[4 * ks + 1];
        const uint4 aB2 = ha4pB[4 * ks + 2], aB3 = ha4pB[4 * ks + 3];
        const float4 xeA = xe_lds[0][s];
        const float4 xeB = xe_lds[1][s];
        h2 a[16], b[16];
        a[0]  = __builtin_bit_cast(h2, aA0.x); a[1]  = __builtin_bit_cast(h2, aA0.y);
        a[2]  = __builtin_bit_cast(h2, aA0.z); a[3]  = __builtin_bit_cast(h2, aA0.w);
        a[4]  = __builtin_bit_cast(h2, aA1.x); a[5]  = __builtin_bit_cast(h2, aA1.y);
        a[6]  = __builtin_bit_cast(h2, aA1.z); a[7]  = __builtin_bit_cast(h2, aA1.w);
        a[8]  = __builtin_bit_cast(h2, aA2.x); a[9]  = __builtin_bit_cast(h2, aA2.y);
        a[10] = __builtin_bit_cast(h2, aA2.z); a[11] = __builtin_bit_cast(h2, aA2.w);
        a[12] = __builtin_bit_cast(h2, aA3.x); a[13] = __builtin_bit_cast(h2, aA3.y);
        a[14] = __builtin_bit_cast(h2, aA3.z); a[15] = __builtin_bit_cast(h2, aA3.w);
        b[0]  = __builtin_bit_cast(h2, aB0.x); b[1]  = __builtin_bit_cast(h2, aB0.y);
        b[2]  = __builtin_bit_cast(h2, aB0.z); b[3]  = __builtin_bit_cast(h2, aB0.w);
        b[4]  = __builtin_bit_cast(h2, aB1.x); b[5]  = __builtin_bit_cast(h2, aB1.y);
        b[6]  = __builtin_bit_cast(h2, aB1.z); b[7]  = __builtin_bit_cast(h2, aB1.w);
        b[8]  = __builtin_bit_cast(h2, aB2.x); b[9]  = __builtin_bit_cast(h2, aB2.y);
        b[10] = __builtin_bit_cast(h2, aB2.z); b[11] = __builtin_bit_cast(h2, aB2.w);
        b[12] = __builtin_bit_cast(h2, aB3.x); b[13] = __builtin_bit_cast(h2, aB3.y);
        b[14] = __builtin_bit_cast(h2, aB3.z); b[15] = __builtin_bit_cast(h2, aB3.w);

        // Off-chain precompute in the DS-wait window (both rows):
        const float kktiA  = xeA.y * tisel;
        const float hpre2A = fmaf(kktiA, iccurA, fmaf(-kktiA, hjsA, hjsA));
        const float icnA   = fmaf(2.0f, __builtin_amdgcn_rcpf(
                               1.0f + __builtin_amdgcn_exp2f(fmaf(m2win, xeA.x, m2bin))), -1.0f);
        const float kktiB  = xeB.y * tisel;
        const float hpre2B = fmaf(kktiB, iccurB, fmaf(-kktiB, hjsB, hjsB));
        const float icnB   = fmaf(2.0f, __builtin_amdgcn_rcpf(
                               1.0f + __builtin_amdgcn_exp2f(fmaf(m2win, xeB.x, m2bin))), -1.0f);

        // ---- REC matvec, both rows: 64 dot2, 16 chains of depth 4 ----
        float p0A[4] = {0,0,0,0}, p1A[4] = {0,0,0,0};
        float p0B[4] = {0,0,0,0}, p1B[4] = {0,0,0,0};
#pragma unroll
        for (int c = 0; c < 4; ++c)
#pragma unroll
            for (int i = 0; i < 4; ++i) {
                p0A[c] = fdot2(wR[0][4 * c + i], a[4 * c + i], p0A[c]);
                p1A[c] = fdot2(wR[1][4 * c + i], a[4 * c + i], p1A[c]);
                p0B[c] = fdot2(wR[0][4 * c + i], b[4 * c + i], p0B[c]);
                p1B[c] = fdot2(wR[1][4 * c + i], b[4 * c + i], p1B[c]);
            }
        const float rs0A = red4((p0A[0] + p0A[1]) + (p0A[2] + p0A[3]));
        const float rs1A = red4((p1A[0] + p1A[1]) + (p1A[2] + p1A[3]));
        const float rs0B = red4((p0B[0] + p0B[1]) + (p0B[2] + p0B[3]));
        const float rs1B = red4((p1B[0] + p1B[1]) + (p1B[2] + p1B[3]));

        const float tresA = fmaf(2.0f, __builtin_amdgcn_rcpf(
                              1.0f + __builtin_amdgcn_exp2f(fmaf(m2, odd ? rs1A : rs0A, bR2m))), -1.0f);
        const float tresB = fmaf(2.0f, __builtin_amdgcn_rcpf(
                              1.0f + __builtin_amdgcn_exp2f(fmaf(m2, odd ? rs1B : rs0B, bR2m))), -1.0f);
        hjsA = fmaf(kktiA, tresA, hpre2A);   // valid on roles 0/1
        hjsB = fmaf(kktiB, tresB, hpre2B);
        iccurA = icnA; iccurB = icnB;
        if (ks < 2) {
            h16hA[2 * jg + ks] = (_Float16)hjsA;
            h16hB[2 * jg + ks] = (_Float16)hjsB;
        }
        __syncthreads();   // B: h_{s+1} visible for both rows

        const uint4 hA0 = h4pA[4 * ks + 0], hA1 = h4pA[4 * ks + 1];
        const uint4 hA2 = h4pA[4 * ks + 2], hA3 = h4pA[4 * ks + 3];
        const uint4 hB0 = h4pB[4 * ks + 0], hB1 = h4pB[4 * ks + 1];
        const uint4 hB2 = h4pB[4 * ks + 2], hB3 = h4pB[4 * ks + 3];
        h2 g[16], f[16];
        g[0]  = __builtin_bit_cast(h2, hA0.x); g[1]  = __builtin_bit_cast(h2, hA0.y);
        g[2]  = __builtin_bit_cast(h2, hA0.z); g[3]  = __builtin_bit_cast(h2, hA0.w);
        g[4]  = __builtin_bit_cast(h2, hA1.x); g[5]  = __builtin_bit_cast(h2, hA1.y);
        g[6]  = __builtin_bit_cast(h2, hA1.z); g[7]  = __builtin_bit_cast(h2, hA1.w);
        g[8]  = __builtin_bit_cast(h2, hA2.x); g[9]  = __builtin_bit_cast(h2, hA2.y);
        g[10] = __builtin_bit_cast(h2, hA2.z); g[11] = __builtin_bit_cast(h2, hA2.w);
        g[12] = __builtin_bit_cast(h2, hA3.x); g[13] = __builtin_bit_cast(h2, hA3.y);
        g[14] = __builtin_bit_cast(h2, hA3.z); g[15] = __builtin_bit_cast(h2, hA3.w);
        f[0]  = __builtin_bit_cast(h2, hB0.x); f[1]  = __builtin_bit_cast(h2, hB0.y);
        f[2]  = __builtin_bit_cast(h2, hB0.z); f[3]  = __builtin_bit_cast(h2, hB0.w);
        f[4]  = __builtin_bit_cast(h2, hB1.x); f[5]  = __builtin_bit_cast(h2, hB1.y);
        f[6]  = __builtin_bit_cast(h2, hB1.z); f[7]  = __builtin_bit_cast(h2, hB1.w);
        f[8]  = __builtin_bit_cast(h2, hB2.x); f[9]  = __builtin_bit_cast(h2, hB2.y);
        f[10] = __builtin_bit_cast(h2, hB2.z); f[11] = __builtin_bit_cast(h2, hB2.w);
        f[12] = __builtin_bit_cast(h2, hB3.x); f[13] = __builtin_bit_cast(h2, hB3.y);
        f[14] = __builtin_bit_cast(h2, hB3.z); f[15] = __builtin_bit_cast(h2, hB3.w);

        // ---- ATT matvec on h_{s+1}, both rows: 64 dot2 ----
        float q0A[4] = {0,0,0,0}, q1A[4] = {0,0,0,0};
        float q0B[4] = {0,0,0,0}, q1B[4] = {0,0,0,0};
#pragma unroll
        for (int c = 0; c < 4; ++c)
#pragma unroll
            for (int i = 0; i < 4; ++i) {
                q0A[c] = fdot2(wA[0][4 * c + i], g[4 * c + i], q0A[c]);
                q1A[c] = fdot2(wA[1][4 * c + i], g[4 * c + i], q1A[c]);
                q0B[c] = fdot2(wA[0][4 * c + i], f[4 * c + i], q0B[c]);
                q1B[c] = fdot2(wA[1][4 * c + i], f[4 * c + i], q1B[c]);
            }
        const float as0A = red4((q0A[0] + q0A[1]) + (q0A[2] + q0A[3]));
        const float as1A = red4((q1A[0] + q1A[1]) + (q1A[2] + q1A[3]));
        const float as0B = red4((q0B[0] + q0B[1]) + (q0B[2] + q0B[3]));
        const float as1B = red4((q1B[0] + q1B[1]) + (q1B[2] + q1B[3]));

        if (s < S_ACC) {
            const float sgA = __builtin_amdgcn_rcpf(
                1.0f + __builtin_amdgcn_exp2f(fmaf(-LOG2E, odd ? as1A : as0A, bA1m)));
            const float sgB = __builtin_amdgcn_rcpf(
                1.0f + __builtin_amdgcn_exp2f(fmaf(-LOG2E, odd ? as1B : as0B, bA1m)));
            if (ks < 2) {
                ha16hA[2 * jg + ks] = (_Float16)(hjsA * sgA);
                ha16hB[2 * jg + ks] = (_Float16)(hjsB * sgB);
            }
        } else {
            // Last 128 steps: fused ACC matvec + role nonlin, both rows.
            float c0A[4] = {0,0,0,0}, c1A[4] = {0,0,0,0};
            float c0B[4] = {0,0,0,0}, c1B[4] = {0,0,0,0};
#pragma unroll
            for (int c = 0; c < 4; ++c)
#pragma unroll
                for (int i = 0; i < 4; ++i) {
                    c0A[c] = fdot2(wC[0][4 * c + i], g[4 * c + i], c0A[c]);
                    c1A[c] = fdot2(wC[1][4 * c + i], g[4 * c + i], c1A[c]);
                    c0B[c] = fdot2(wC[0][4 * c + i], f[4 * c + i], c0B[c]);
                    c1B[c] = fdot2(wC[1][4 * c + i], f[4 * c + i], c1B[c]);
                }
            const float cs0A = red4((c0A[0] + c0A[1]) + (c0A[2] + c0A[3]));
            const float cs1A = red4((c1A[0] + c1A[1]) + (c1A[2] + c1A[3]));
            const float cs0B = red4((c0B[0] + c0B[1]) + (c0B[2] + c0B[3]));
            const float cs1B = red4((c1B[0] + c1B[1]) + (c1B[2] + c1B[3]));
            const float sumA = low ? (odd ? as1A : as0A) : (odd ? cs1A : cs0A);
            const float sumB = low ? (odd ? as1B : as0B) : (odd ? cs1B : cs0B);
            const float fvA = __builtin_amdgcn_rcpf(
                1.0f + __builtin_amdgcn_exp2f(fmaf(preF, sumA, preFb)));
            const float fvB = __builtin_amdgcn_rcpf(
                1.0f + __builtin_amdgcn_exp2f(fmaf(preF, sumB, preFb)));
            const float frA = fmaf(postm, fvA, posta);
            const float frB = fmaf(postm, fvB, posta);
            if (ks < 2) {
                ha16hA[2 * jg + ks] = (_Float16)(hjsA * frA);  // frA = sigmoid on roles 0/1
                ha16hB[2 * jg + ks] = (_Float16)(hjsB * frB);
            }
            acsA = fmaf(xeA.z, frA, 0.9f * acsA);   // roles 2/3 (frA = tanh)
            acsB = fmaf(xeB.z, frB, 0.9f * acsB);
        }
    }

    // ---- Outputs: out[rX] = sum_j (h_f + acc_f)[j] * W_out[j] + b_out ----
    float valA = (low ? hjsA : acsA) * wosel;
    float valB = (low ? hjsB : acsB) * wosel;
#pragma unroll
    for (int m = 1; m < 64; m <<= 1) {
        valA += __shfl_xor(valA, m);
        valB += __shfl_xor(valB, m);
    }
    const int wave = t >> 6, lane = t & 63;
    if (lane == 0) { red_s[wave] = valA; red_s[4 + wave] = valB; }
    __syncthreads();
    if (t == 0) {
        float o = bout;
#pragma unroll
        for (int w = 0; w < 4; ++w) o += red_s[w];
        out[rA] = o;
    }
    if (t == 1) {
        float o = bout;
#pragma unroll
        for (int w = 0; w < 4; ++w) o += red_s[4 + w];
        out[rB] = o;
    }
}

extern "C" void kernel_launch(void* const* d_in, const int* in_sizes, int n_in,
                              void* d_out, int out_size, void* d_ws, size_t ws_size,
                              hipStream_t stream) {
    const float* x     = (const float*)d_in[0];
    const float* W_in  = (const float*)d_in[1];
    const float* b_in  = (const float*)d_in[2];
    const float* W_rec = (const float*)d_in[3];
    const float* b_rec = (const float*)d_in[4];
    const float* tau   = (const float*)d_in[5];
    const float* W_att = (const float*)d_in[6];
    const float* b_att = (const float*)d_in[7];
    const float* W_ev  = (const float*)d_in[8];
    const float* b_ev  = (const float*)d_in[9];
    const float* W_acc = (const float*)d_in[10];
    const float* b_acc = (const float*)d_in[11];
    const float* W_out = (const float*)d_in[12];
    const float* b_out = (const float*)d_in[13];

    float* out    = (float*)d_out;        // [256,1]
    float* out_ew = out + 256;            // [256,2048]

    clnm_kernel<<<128, 256, 0, stream>>>(x, W_in, b_in, W_rec, b_rec, tau,
                                         W_att, b_att, W_ev, b_ev,
                                         W_acc, b_acc, W_out, b_out,
                                         out, out_ew);
}

// Round 15
// 1659.776 us; speedup vs baseline: 1.0225x; 1.0225x over previous
//
#include <hip/hip_runtime.h>

#define DT_C 0.1f
#define LOG2E 1.4426950408889634f
#define S_ACC 1920   // acc weight 0.9^(2047-t): t<1920 contributes <1.4e-6

typedef _Float16 v8h __attribute__((ext_vector_type(8)));
typedef _Float16 h4  __attribute__((ext_vector_type(4)));
typedef float    v4f __attribute__((ext_vector_type(4)));

__device__ __forceinline__ float sigx(float z) {
    return __builtin_amdgcn_rcpf(1.0f + __builtin_amdgcn_exp2f(-LOG2E * z));
}

// B=256, S=2048, I=1, H=128, O=1.
// R15: BATCH-MFMA. Grid 16 blocks x 256 threads (4 waves). Block br owns batch
// rows [16br,16br+16). Per step each matvec is a [16x128]x[128x128] GEMM:
// wave w owns j in [32w,32w+32) = 2 N-tiles; 4 K-tiles -> 8 MFMA
// (mfma_f32_16x16x32_f16) per matvec, B-frags (weights) resident in VGPRs.
// h state is fp32 IN REGISTERS in C-layout (row b=(l>>4)*4+reg, col j=l&15+16nt);
// LDS holds only the f16 exchange copies (h_l, ha_l) for A-frags + pre-staged
// per-step scalars x_pack/e_pack[s][b] f16 (one b64 read per lane per step).
// Same 2-barrier skeleton as R10-R13 (verified). Layouts per HW-verified guide:
// A[m=l&15][k=(l>>4)*8+i], B[n=l&15][k=(l>>4)*8+i], C[row=(l>>4)*4+reg][col=l&15].
__global__ __attribute__((amdgpu_waves_per_eu(1, 1))) __launch_bounds__(256)
void clnm_kernel(const float* __restrict__ x,      // [256,2048]
                 const float* __restrict__ W_in,   // [128,1]
                 const float* __restrict__ b_in,   // [128]
                 const float* __restrict__ W_rec,  // [128,128]
                 const float* __restrict__ b_rec,  // [128]
                 const float* __restrict__ tau,    // [128]
                 const float* __restrict__ W_att,  // [128,128]
                 const float* __restrict__ b_att,  // [128]
                 const float* __restrict__ W_ev,   // [1,2]
                 const float* __restrict__ b_ev,   // [1]
                 const float* __restrict__ W_acc,  // [128,128]
                 const float* __restrict__ b_acc,  // [128]
                 const float* __restrict__ W_out,  // [1,128]
                 const float* __restrict__ b_out,  // [1]
                 float* __restrict__ out,          // [256]
                 float* __restrict__ out_ew)       // [256,2048]
{
    const int t   = threadIdx.x;
    const int w   = t >> 6;       // wave 0..3: owns j in [32w, 32w+32)
    const int l   = t & 63;
    const int col = l & 15;       // A row (batch) on reads; C col (j) on outputs
    const int qr  = l >> 4;       // quad
    const int rb0 = blockIdx.x * 16;

    __shared__ __align__(16) _Float16 x_pack[2048][16];  // [s][b] 64 KB
    __shared__ __align__(16) _Float16 e_pack[2048][16];  // [s][b] 64 KB
    __shared__ __align__(16) _Float16 h_l[16][136];      // [b][j], +8 pad
    __shared__ __align__(16) _Float16 ha_l[16][136];
    __shared__ float ws_red[4][4][4];                    // [wave][qr][reg]

    const float wev0 = W_ev[0], wev1 = W_ev[1], bev = b_ev[0], bout = b_out[0];

    // ---- init: ew precompute (f32->global exact; f16->LDS), x->LDS f16 ----
    {
        const int pb = t >> 4;          // batch row 0..15
        const int pc = t & 15;          // 128-step chunk
        const float* xg = x + (size_t)(rb0 + pb) * 2048;
        float* ewg = out_ew + (size_t)(rb0 + pb) * 2048;
        const int s0 = pc * 128;
        float prev = (s0 == 0) ? 0.0f : xg[s0 - 1];
        for (int i = 0; i < 128; ++i) {
            const int s = s0 + i;
            const float xv = xg[s];
            const float ew = (s == 0) ? 0.0f
                           : sigx(fmaf(wev0, xv, fmaf(wev1, prev, bev)));
            prev = xv;
            x_pack[s][pb] = (_Float16)xv;
            e_pack[s][pb] = (_Float16)ew;
            ewg[s] = ew;
        }
        for (int idx = t; idx < 16 * 136; idx += 256) {
            h_l[idx / 136][idx % 136]  = (_Float16)0.0f;
            ha_l[idx / 136][idx % 136] = (_Float16)0.0f;
        }
    }

    // ---- weight B-fragments: wB[mat][nt][kt], mat 0=rec 1=att 2=acc ----
    v8h wB[3][2][4];
    {
        const float* const Wm[3] = {W_rec, W_att, W_acc};
#pragma unroll
        for (int m = 0; m < 3; ++m)
#pragma unroll
            for (int nt = 0; nt < 2; ++nt)
#pragma unroll
                for (int kt = 0; kt < 4; ++kt) {
                    const float* p = Wm[m] + (32 * w + 16 * nt + col) * 128
                                   + 32 * kt + qr * 8;
                    const float4 f0 = *(const float4*)p;
                    const float4 f1 = *(const float4*)(p + 4);
                    v8h f = {(_Float16)f0.x, (_Float16)f0.y, (_Float16)f0.z, (_Float16)f0.w,
                             (_Float16)f1.x, (_Float16)f1.y, (_Float16)f1.z, (_Float16)f1.w};
                    wB[m][nt][kt] = f;
                }
    }

    // ---- per-lane constants for my 2 output columns jA, jB ----
    const int jA = 32 * w + col, jB = jA + 16;
    const float m2 = -2.0f * LOG2E;
    float bR2m[2], m2win[2], m2bin[2], bA1m[2], bC2m[2], ti[2], wo[2];
#pragma unroll
    for (int nt = 0; nt < 2; ++nt) {
        const int j = nt ? jB : jA;
        bR2m[nt]  = m2 * b_rec[j];
        m2win[nt] = m2 * W_in[j];
        m2bin[nt] = m2 * b_in[j];
        bA1m[nt]  = -LOG2E * b_att[j];
        bC2m[nt]  = m2 * b_acc[j];
        ti[nt]    = 1.0f / fminf(fmaxf(tau[j], 0.1f), 10.0f);
        wo[nt]    = W_out[j];
    }

    float hr[2][4] = {{0.f,0.f,0.f,0.f},{0.f,0.f,0.f,0.f}};  // h fp32, C-layout
    float ac[2][4] = {{0.f,0.f,0.f,0.f},{0.f,0.f,0.f,0.f}};  // acc fp32

    for (int s = 0; s < 2048; ++s) {
        __syncthreads();   // A: ha_l(s) + (s=0) init visible

        // ---- tick1: REC = A(hatt) x B(W_rec) ----
        const h4 x4 = *(const h4*)&x_pack[s][qr * 4];
        const h4 e4 = *(const h4*)&e_pack[s][qr * 4];
        v4f c0 = {0.f,0.f,0.f,0.f}, c1 = {0.f,0.f,0.f,0.f};
#pragma unroll
        for (int kt = 0; kt < 4; ++kt) {
            const v8h a = *(const v8h*)&ha_l[col][32 * kt + qr * 8];
            c0 = __builtin_amdgcn_mfma_f32_16x16x32_f16(a, wB[0][0][kt], c0, 0, 0, 0);
            c1 = __builtin_amdgcn_mfma_f32_16x16x32_f16(a, wB[0][1][kt], c1, 0, 0, 0);
        }
        float kk[4], ep[4], xf[4];
#pragma unroll
        for (int reg = 0; reg < 4; ++reg) {
            const float ew = (float)e4[reg];
            kk[reg] = DT_C * (1.0f + ew);
            ep[reg] = 0.1f * ew;
            xf[reg] = (float)x4[reg];
        }
#pragma unroll
        for (int nt = 0; nt < 2; ++nt) {
            const v4f c = nt ? c1 : c0;
#pragma unroll
            for (int reg = 0; reg < 4; ++reg) {
                const float rec = fmaf(2.0f, __builtin_amdgcn_rcpf(
                    1.0f + __builtin_amdgcn_exp2f(fmaf(m2, c[reg], bR2m[nt]))), -1.0f);
                const float icv = fmaf(2.0f, __builtin_amdgcn_rcpf(
                    1.0f + __builtin_amdgcn_exp2f(fmaf(m2win[nt], xf[reg], m2bin[nt]))), -1.0f);
                const float kkti = kk[reg] * ti[nt];
                float h = hr[nt][reg];
                h = fmaf(kkti, (icv + rec) - h, h);
                hr[nt][reg] = h;
                h_l[qr * 4 + reg][32 * w + 16 * nt + col] = (_Float16)h;
            }
        }
        __syncthreads();   // B: h_{s+1} f16 copy visible

        // ---- tick2: ATT (+ACC late) on h_{s+1} ----
        v4f d0 = {0.f,0.f,0.f,0.f}, d1 = {0.f,0.f,0.f,0.f};
#pragma unroll
        for (int kt = 0; kt < 4; ++kt) {
            const v8h a = *(const v8h*)&h_l[col][32 * kt + qr * 8];
            d0 = __builtin_amdgcn_mfma_f32_16x16x32_f16(a, wB[1][0][kt], d0, 0, 0, 0);
            d1 = __builtin_amdgcn_mfma_f32_16x16x32_f16(a, wB[1][1][kt], d1, 0, 0, 0);
        }
        if (s < S_ACC) {
#pragma unroll
            for (int nt = 0; nt < 2; ++nt) {
                const v4f d = nt ? d1 : d0;
#pragma unroll
                for (int reg = 0; reg < 4; ++reg) {
                    const float att = __builtin_amdgcn_rcpf(
                        1.0f + __builtin_amdgcn_exp2f(fmaf(-LOG2E, d[reg], bA1m[nt])));
                    ha_l[qr * 4 + reg][32 * w + 16 * nt + col] =
                        (_Float16)(hr[nt][reg] * att);
                }
            }
        } else {
            v4f g0 = {0.f,0.f,0.f,0.f}, g1 = {0.f,0.f,0.f,0.f};
#pragma unroll
            for (int kt = 0; kt < 4; ++kt) {
                const v8h a = *(const v8h*)&h_l[col][32 * kt + qr * 8];
                g0 = __builtin_amdgcn_mfma_f32_16x16x32_f16(a, wB[2][0][kt], g0, 0, 0, 0);
                g1 = __builtin_amdgcn_mfma_f32_16x16x32_f16(a, wB[2][1][kt], g1, 0, 0, 0);
            }
#pragma unroll
            for (int nt = 0; nt < 2; ++nt) {
                const v4f d = nt ? d1 : d0;
                const v4f g = nt ? g1 : g0;
#pragma unroll
                for (int reg = 0; reg < 4; ++reg) {
                    const float att = __builtin_amdgcn_rcpf(
                        1.0f + __builtin_amdgcn_exp2f(fmaf(-LOG2E, d[reg], bA1m[nt])));
                    ha_l[qr * 4 + reg][32 * w + 16 * nt + col] =
                        (_Float16)(hr[nt][reg] * att);
                    const float ct = fmaf(2.0f, __builtin_amdgcn_rcpf(
                        1.0f + __builtin_amdgcn_exp2f(fmaf(m2, g[reg], bC2m[nt]))), -1.0f);
                    ac[nt][reg] = fmaf(ep[reg], ct, 0.9f * ac[nt][reg]);
                }
            }
        }
    }

    // ---- Output: out[b] = sum_j (h+acc)[b][j] * W_out[j] + b_out ----
    float pv[4];
#pragma unroll
    for (int reg = 0; reg < 4; ++reg)
        pv[reg] = fmaf(hr[0][reg] + ac[0][reg], wo[0],
                       (hr[1][reg] + ac[1][reg]) * wo[1]);
#pragma unroll
    for (int m = 1; m < 16; m <<= 1)
#pragma unroll
        for (int reg = 0; reg < 4; ++reg)
            pv[reg] += __shfl_xor(pv[reg], m);
    if (col == 0) {
#pragma unroll
        for (int reg = 0; reg < 4; ++reg) ws_red[w][qr][reg] = pv[reg];
    }
    __syncthreads();
    if (t < 16) {
        float o = bout;
#pragma unroll
        for (int w2 = 0; w2 < 4; ++w2) o += ws_red[w2][t >> 2][t & 3];
        out[rb0 + t] = o;
    }
}

extern "C" void kernel_launch(void* const* d_in, const int* in_sizes, int n_in,
                              void* d_out, int out_size, void* d_ws, size_t ws_size,
                              hipStream_t stream) {
    const float* x     = (const float*)d_in[0];
    const float* W_in  = (const float*)d_in[1];
    const float* b_in  = (const float*)d_in[2];
    const float* W_rec = (const float*)d_in[3];
    const float* b_rec = (const float*)d_in[4];
    const float* tau   = (const float*)d_in[5];
    const float* W_att = (const float*)d_in[6];
    const float* b_att = (const float*)d_in[7];
    const float* W_ev  = (const float*)d_in[8];
    const float* b_ev  = (const float*)d_in[9];
    const float* W_acc = (const float*)d_in[10];
    const float* b_acc = (const float*)d_in[11];
    const float* W_out = (const float*)d_in[12];
    const float* b_out = (const float*)d_in[13];

    float* out    = (float*)d_out;        // [256,1]
    float* out_ew = out + 256;            // [256,2048]

    clnm_kernel<<<16, 256, 0, stream>>>(x, W_in, b_in, W_rec, b_rec, tau,
                                        W_att, b_att, W_ev, b_ev,
                                        W_acc, b_acc, W_out, b_out,
                                        out, out_ew);
}

// Round 16
// 1617.805 us; speedup vs baseline: 1.0490x; 1.0259x over previous
//
#include <hip/hip_runtime.h>

#define DT_C 0.1f
#define LOG2E 1.4426950408889634f
#define S_ACC 1920   // acc weight 0.9^(2047-t): t<1920 contributes <1.4e-6

typedef _Float16 v8h __attribute__((ext_vector_type(8)));
typedef _Float16 h4  __attribute__((ext_vector_type(4)));
typedef float    v4f __attribute__((ext_vector_type(4)));

__device__ __forceinline__ float sigx(float z) {
    return __builtin_amdgcn_rcpf(1.0f + __builtin_amdgcn_exp2f(-LOG2E * z));
}

// B=256, S=2048, I=1, H=128, O=1.
// R16: MFMA v2. Grid 16 blocks x 512 threads (8 waves, 2/SIMD). Block owns
// batch rows [16br,16br+16); wave w owns j in [16w,16w+16) (ONE N-tile).
// R15 lesson: MFMA fixed the matvec but each lane owned 8 C-cells -> ~24
// transcendental sequences/lane/step of epilogue issue on 16 CUs with no
// TLP. v2 halves cells/lane (4), halves B-frag VGPRs, halves per-tick MFMAs
// (2 chains of 2 + add -> shorter dep chain), and runs 2 waves/SIMD.
// Next-step ic/kkti/hpre2 precomputed in tick2's shadow (R13 trick) so
// tick1's chain is MFMA -> tanh -> fma -> cvt -> write.
// Layouts (HW-verified R15): A[m=l&15][k=(l>>4)*8+i] (m=batch row),
// B[n=l&15][k=(l>>4)*8+i] (n=j, holds W[j][k]), C[row=(l>>4)*4+reg][col=l&15].
__global__ __attribute__((amdgpu_waves_per_eu(2, 2))) __launch_bounds__(512)
void clnm_kernel(const float* __restrict__ x,      // [256,2048]
                 const float* __restrict__ W_in,   // [128,1]
                 const float* __restrict__ b_in,   // [128]
                 const float* __restrict__ W_rec,  // [128,128]
                 const float* __restrict__ b_rec,  // [128]
                 const float* __restrict__ tau,    // [128]
                 const float* __restrict__ W_att,  // [128,128]
                 const float* __restrict__ b_att,  // [128]
                 const float* __restrict__ W_ev,   // [1,2]
                 const float* __restrict__ b_ev,   // [1]
                 const float* __restrict__ W_acc,  // [128,128]
                 const float* __restrict__ b_acc,  // [128]
                 const float* __restrict__ W_out,  // [1,128]
                 const float* __restrict__ b_out,  // [1]
                 float* __restrict__ out,          // [256]
                 float* __restrict__ out_ew)       // [256,2048]
{
    const int t   = threadIdx.x;
    const int w   = t >> 6;       // wave 0..7: owns j in [16w, 16w+16)
    const int l   = t & 63;
    const int col = l & 15;       // A m (batch row) on reads; C col (j) on outputs
    const int qr  = l >> 4;
    const int rb0 = blockIdx.x * 16;

    __shared__ __align__(16) _Float16 x_pack[2048][16];  // [s][b] 64 KB
    __shared__ __align__(16) _Float16 e_pack[2048][16];  // [s][b] 64 KB
    __shared__ __align__(16) _Float16 h_l[16][136];      // [b][j], +8 pad
    __shared__ __align__(16) _Float16 ha_l[16][136];
    __shared__ float ws_red[8][4][4];                    // [wave][qr][reg]

    const float wev0 = W_ev[0], wev1 = W_ev[1], bev = b_ev[0], bout = b_out[0];

    // ---- init: ew precompute (f32->global exact; f16->LDS), x->LDS f16 ----
    {
        const int pb = t >> 5;          // batch row 0..15
        const int pc = t & 31;          // 64-step chunk
        const float* xg = x + (size_t)(rb0 + pb) * 2048;
        float* ewg = out_ew + (size_t)(rb0 + pb) * 2048;
        const int s0 = pc * 64;
        float prev = (s0 == 0) ? 0.0f : xg[s0 - 1];
        for (int i = 0; i < 64; ++i) {
            const int s = s0 + i;
            const float xv = xg[s];
            const float ew = (s == 0) ? 0.0f
                           : sigx(fmaf(wev0, xv, fmaf(wev1, prev, bev)));
            prev = xv;
            x_pack[s][pb] = (_Float16)xv;
            e_pack[s][pb] = (_Float16)ew;
            ewg[s] = ew;
        }
        for (int idx = t; idx < 16 * 136; idx += 512) {
            h_l[idx / 136][idx % 136]  = (_Float16)0.0f;
            ha_l[idx / 136][idx % 136] = (_Float16)0.0f;
        }
    }

    // ---- weight B-fragments: wB[mat][kt], mat 0=rec 1=att 2=acc ----
    v8h wB[3][4];
    {
        const float* const Wm[3] = {W_rec, W_att, W_acc};
#pragma unroll
        for (int m = 0; m < 3; ++m)
#pragma unroll
            for (int kt = 0; kt < 4; ++kt) {
                const float* p = Wm[m] + (16 * w + col) * 128 + 32 * kt + qr * 8;
                const float4 f0 = *(const float4*)p;
                const float4 f1 = *(const float4*)(p + 4);
                wB[m][kt] = v8h{(_Float16)f0.x, (_Float16)f0.y, (_Float16)f0.z,
                                (_Float16)f0.w, (_Float16)f1.x, (_Float16)f1.y,
                                (_Float16)f1.z, (_Float16)f1.w};
            }
    }

    // ---- per-lane constants for my single output column j ----
    const int j = 16 * w + col;
    const float m2 = -2.0f * LOG2E;
    const float bR2m  = m2 * b_rec[j];
    const float m2win = m2 * W_in[j];
    const float m2bin = m2 * b_in[j];
    const float bA1m  = -LOG2E * b_att[j];
    const float bC2m  = m2 * b_acc[j];
    const float ti    = 1.0f / fminf(fmaxf(tau[j], 0.1f), 10.0f);
    const float wo    = W_out[j];

    __syncthreads();   // staging + zeros visible

    float hr[4] = {0.f,0.f,0.f,0.f};   // h fp32, C-layout (row b=qr*4+reg)
    float ac[4] = {0.f,0.f,0.f,0.f};
    float kkti[4], hpre2[4], ep[4];
    {
        // Step-0 precompute: ew(0)=0 for all rows -> kk = DT_C; h=0 -> hpre2=kkti*ic.
        const h4 x4 = *(const h4*)&x_pack[0][qr * 4];
#pragma unroll
        for (int reg = 0; reg < 4; ++reg) {
            kkti[reg] = DT_C * ti;
            ep[reg]   = 0.0f;
            const float icv = fmaf(2.0f, __builtin_amdgcn_rcpf(
                1.0f + __builtin_amdgcn_exp2f(fmaf(m2win, (float)x4[reg], m2bin))), -1.0f);
            hpre2[reg] = kkti[reg] * icv;
        }
    }

    for (int s = 0; s < 2048; ++s) {
        __syncthreads();   // A: ha_l(s) visible (s=0: zeros)

        // ---- tick1: REC = A(hatt) x B(W_rec), 2 chains of 2 + add ----
        {
            const v8h a0 = *(const v8h*)&ha_l[col][qr * 8];
            const v8h a1 = *(const v8h*)&ha_l[col][32 + qr * 8];
            const v8h a2 = *(const v8h*)&ha_l[col][64 + qr * 8];
            const v8h a3 = *(const v8h*)&ha_l[col][96 + qr * 8];
            v4f z = {0.f,0.f,0.f,0.f};
            v4f c01 = __builtin_amdgcn_mfma_f32_16x16x32_f16(a1, wB[0][1],
                      __builtin_amdgcn_mfma_f32_16x16x32_f16(a0, wB[0][0], z, 0,0,0), 0,0,0);
            v4f c23 = __builtin_amdgcn_mfma_f32_16x16x32_f16(a3, wB[0][3],
                      __builtin_amdgcn_mfma_f32_16x16x32_f16(a2, wB[0][2], z, 0,0,0), 0,0,0);
            const v4f c = c01 + c23;
#pragma unroll
            for (int reg = 0; reg < 4; ++reg) {
                const float tres = fmaf(2.0f, __builtin_amdgcn_rcpf(
                    1.0f + __builtin_amdgcn_exp2f(fmaf(m2, c[reg], bR2m))), -1.0f);
                const float h = fmaf(kkti[reg], tres, hpre2[reg]);
                hr[reg] = h;
                h_l[qr * 4 + reg][j] = (_Float16)h;
            }
        }
        __syncthreads();   // B: h_{s+1} f16 copy visible

        // ---- tick2: ATT (+ACC late) on h_{s+1} ----
        {
            const v8h a0 = *(const v8h*)&h_l[col][qr * 8];
            const v8h a1 = *(const v8h*)&h_l[col][32 + qr * 8];
            const v8h a2 = *(const v8h*)&h_l[col][64 + qr * 8];
            const v8h a3 = *(const v8h*)&h_l[col][96 + qr * 8];
            v4f z = {0.f,0.f,0.f,0.f};
            v4f d01 = __builtin_amdgcn_mfma_f32_16x16x32_f16(a1, wB[1][1],
                      __builtin_amdgcn_mfma_f32_16x16x32_f16(a0, wB[1][0], z, 0,0,0), 0,0,0);
            v4f d23 = __builtin_amdgcn_mfma_f32_16x16x32_f16(a3, wB[1][3],
                      __builtin_amdgcn_mfma_f32_16x16x32_f16(a2, wB[1][2], z, 0,0,0), 0,0,0);
            const v4f d = d01 + d23;
            if (s < S_ACC) {
#pragma unroll
                for (int reg = 0; reg < 4; ++reg) {
                    const float att = __builtin_amdgcn_rcpf(
                        1.0f + __builtin_amdgcn_exp2f(fmaf(-LOG2E, d[reg], bA1m)));
                    ha_l[qr * 4 + reg][j] = (_Float16)(hr[reg] * att);
                }
            } else {
                v4f g01 = __builtin_amdgcn_mfma_f32_16x16x32_f16(a1, wB[2][1],
                          __builtin_amdgcn_mfma_f32_16x16x32_f16(a0, wB[2][0], z, 0,0,0), 0,0,0);
                v4f g23 = __builtin_amdgcn_mfma_f32_16x16x32_f16(a3, wB[2][3],
                          __builtin_amdgcn_mfma_f32_16x16x32_f16(a2, wB[2][2], z, 0,0,0), 0,0,0);
                const v4f g = g01 + g23;
#pragma unroll
                for (int reg = 0; reg < 4; ++reg) {
                    const float att = __builtin_amdgcn_rcpf(
                        1.0f + __builtin_amdgcn_exp2f(fmaf(-LOG2E, d[reg], bA1m)));
                    ha_l[qr * 4 + reg][j] = (_Float16)(hr[reg] * att);
                    const float ct = fmaf(2.0f, __builtin_amdgcn_rcpf(
                        1.0f + __builtin_amdgcn_exp2f(fmaf(m2, g[reg], bC2m))), -1.0f);
                    ac[reg] = fmaf(ep[reg], ct, 0.9f * ac[reg]);
                }
            }
        }

        // ---- off-chain: precompute kkti/ep/hpre2 for step s+1 ----
        {
            const int sn = (s < 2047) ? s + 1 : 2047;
            const h4 x4 = *(const h4*)&x_pack[sn][qr * 4];
            const h4 e4 = *(const h4*)&e_pack[sn][qr * 4];
#pragma unroll
            for (int reg = 0; reg < 4; ++reg) {
                const float ew = (float)e4[reg];
                const float kt2 = DT_C * (1.0f + ew) * ti;
                kkti[reg] = kt2;
                ep[reg]   = 0.1f * ew;
                const float icv = fmaf(2.0f, __builtin_amdgcn_rcpf(
                    1.0f + __builtin_amdgcn_exp2f(fmaf(m2win, (float)x4[reg], m2bin))), -1.0f);
                hpre2[reg] = fmaf(kt2, icv, fmaf(-kt2, hr[reg], hr[reg]));
            }
        }
    }

    // ---- Output: out[b] = sum_j (h+acc)[b][j] * W_out[j] + b_out ----
    float pv[4];
#pragma unroll
    for (int reg = 0; reg < 4; ++reg)
        pv[reg] = (hr[reg] + ac[reg]) * wo;
#pragma unroll
    for (int m = 1; m < 16; m <<= 1)
#pragma unroll
        for (int reg = 0; reg < 4; ++reg)
            pv[reg] += __shfl_xor(pv[reg], m);
    if (col == 0) {
#pragma unroll
        for (int reg = 0; reg < 4; ++reg) ws_red[w][qr][reg] = pv[reg];
    }
    __syncthreads();
    if (t < 16) {
        float o = bout;
#pragma unroll
        for (int w2 = 0; w2 < 8; ++w2) o += ws_red[w2][t >> 2][t & 3];
        out[rb0 + t] = o;
    }
}

extern "C" void kernel_launch(void* const* d_in, const int* in_sizes, int n_in,
                              void* d_out, int out_size, void* d_ws, size_t ws_size,
                              hipStream_t stream) {
    const float* x     = (const float*)d_in[0];
    const float* W_in  = (const float*)d_in[1];
    const float* b_in  = (const float*)d_in[2];
    const float* W_rec = (const float*)d_in[3];
    const float* b_rec = (const float*)d_in[4];
    const float* tau   = (const float*)d_in[5];
    const float* W_att = (const float*)d_in[6];
    const float* b_att = (const float*)d_in[7];
    const float* W_ev  = (const float*)d_in[8];
    const float* b_ev  = (const float*)d_in[9];
    const float* W_acc = (const float*)d_in[10];
    const float* b_acc = (const float*)d_in[11];
    const float* W_out = (const float*)d_in[12];
    const float* b_out = (const float*)d_in[13];

    float* out    = (float*)d_out;        // [256,1]
    float* out_ew = out + 256;            // [256,2048]

    clnm_kernel<<<16, 512, 0, stream>>>(x, W_in, b_in, W_rec, b_rec, tau,
                                        W_att, b_att, W_ev, b_ev,
                                        W_acc, b_acc, W_out, b_out,
                                        out, out_ew);
}